// Round 14
// baseline (520.387 us; speedup 1.0000x reference)
//
#include <hip/hip_runtime.h>
#include <hip/hip_bf16.h>

#define BTOK 8192
#define DDIM 1024
#define NEXP 8
#define KCAP 2048
#define HDIM 4096
#define MB ((size_t)1048576)

typedef __attribute__((ext_vector_type(4))) float f32x4;
typedef __attribute__((ext_vector_type(8))) short bf16x8;

__device__ __forceinline__ unsigned short f2bf(float f) {
    union { float f; unsigned u; } v; v.f = f;
    unsigned r = v.u + 0x7fffu + ((v.u >> 16) & 1u);   // RNE
    return (unsigned short)(r >> 16);
}
__device__ __forceinline__ float bf2f(unsigned short u) {
    union { unsigned u; float f; } v; v.u = ((unsigned)u) << 16;
    return v.f;
}

typedef __attribute__((address_space(3))) unsigned int lds_u32;
typedef __attribute__((address_space(1))) const unsigned int glb_u32;
__device__ __forceinline__ void gl_lds16(const void* g, void* l) {
    __builtin_amdgcn_global_load_lds((glb_u32*)g, (lds_u32*)l, 16, 0, 0);
}

// ======== prep: router (blocks 0..2047, + inv=-1 init) and W-transpose (blocks 2048+) ========
__global__ __launch_bounds__(256) void prep_kernel(
    const float* __restrict__ x, const float* __restrict__ Wr,
    const float* __restrict__ br, const float* __restrict__ W1,
    const float* __restrict__ W2, float* __restrict__ gateT,
    unsigned short* __restrict__ xb, unsigned short* __restrict__ w1t,
    unsigned short* __restrict__ w2t, int* __restrict__ inv) {
    __shared__ char smem[NEXP * DDIM * 4];     // router: wr_s 32KB; tcvt: tile 9KB
    int bid = blockIdx.x;
    int t = threadIdx.x;
    if (bid < BTOK / 4) {
        // ---- router role: gateT[e][b] = softmax(x@Wr + br); x->bf16; inv init ----
        float (*wr_s)[DDIM] = (float (*)[DDIM])smem;
        for (int i = t; i < NEXP * DDIM; i += 256) {
            int e = i >> 10, d = i & 1023;
            wr_s[e][d] = Wr[d * NEXP + e];
        }
        if (t < 32) inv[(size_t)(t >> 2) * BTOK + bid * 4 + (t & 3)] = -1;  // all 8 e x 4 b
        __syncthreads();
        int wid = t >> 6, lane = t & 63;
        int b = bid * 4 + wid;
        const float4* xr = (const float4*)(x + (size_t)b * DDIM);
        float4 xv[4];
#pragma unroll
        for (int j = 0; j < 4; j++) xv[j] = xr[j * 64 + lane];
#pragma unroll
        for (int j = 0; j < 4; j++) {
            short4 s;
            s.x = (short)f2bf(xv[j].x); s.y = (short)f2bf(xv[j].y);
            s.z = (short)f2bf(xv[j].z); s.w = (short)f2bf(xv[j].w);
            *(short4*)(xb + (size_t)b * DDIM + (j * 64 + lane) * 4) = s;
        }
        double acc[NEXP];
#pragma unroll
        for (int e = 0; e < NEXP; e++) {
            double a = 0.0;
#pragma unroll
            for (int j = 0; j < 4; j++) {
                float4 wv = ((const float4*)&wr_s[e][0])[j * 64 + lane];
                a += (double)xv[j].x * wv.x + (double)xv[j].y * wv.y
                   + (double)xv[j].z * wv.z + (double)xv[j].w * wv.w;
            }
#pragma unroll
            for (int s = 1; s < 64; s <<= 1) a += __shfl_xor(a, s, 64);
            acc[e] = a + (double)br[e];
        }
        if (lane == 0) {
            double mx = acc[0];
#pragma unroll
            for (int e = 1; e < NEXP; e++) mx = fmax(mx, acc[e]);
            double p[NEXP]; double ssum = 0.0;
#pragma unroll
            for (int e = 0; e < NEXP; e++) { p[e] = exp(acc[e] - mx); ssum += p[e]; }
            double is = 1.0 / ssum;
#pragma unroll
            for (int e = 0; e < NEXP; e++) gateT[e * BTOK + b] = (float)(p[e] * is);
        }
    } else {
        // ---- tcvt role: W1 (z<8) / W2 (z>=8), [R][C] f32 -> [C][R] bf16 ----
        int z16 = bid - BTOK / 4;          // 0..16383
        int z = z16 >> 10, bx = z16 & 1023;
        const float* src; unsigned short* dst; int R, C;
        if (z < 8) { src = W1 + (size_t)z * DDIM * HDIM; dst = w1t + (size_t)z * DDIM * HDIM; R = DDIM; C = HDIM; }
        else       { src = W2 + (size_t)(z - 8) * DDIM * HDIM; dst = w2t + (size_t)(z - 8) * DDIM * HDIM; R = HDIM; C = DDIM; }
        int ntx = C >> 6;
        int c0 = (bx % ntx) * 64, r0 = (bx / ntx) * 64;
        unsigned short (*tile)[72] = (unsigned short (*)[72])smem;
        int cq = t & 15, rr = t >> 4;
#pragma unroll
        for (int ri = 0; ri < 4; ri++) {
            int r = ri * 16 + rr;
            float4 v = *(const float4*)(src + (size_t)(r0 + r) * C + c0 + cq * 4);
            tile[cq * 4 + 0][r] = f2bf(v.x);
            tile[cq * 4 + 1][r] = f2bf(v.y);
            tile[cq * 4 + 2][r] = f2bf(v.z);
            tile[cq * 4 + 3][r] = f2bf(v.w);
        }
        __syncthreads();
        int rq = t & 15, cc = t >> 4;
#pragma unroll
        for (int ci = 0; ci < 4; ci++) {
            int c = ci * 16 + cc;
            *(short4*)(dst + (size_t)(c0 + c) * R + r0 + rq * 4) = *(const short4*)&tile[c][rq * 4];
        }
    }
}

// ---- fused route: radix select + compaction + ties + inverse map, one block/expert ----
__global__ __launch_bounds__(256) void route_kernel(
    const float* __restrict__ gateT, int* __restrict__ idx_list,
    float* __restrict__ wt_list, int* __restrict__ inv) {
    int e = blockIdx.x, t = threadIdx.x;
    const float* g = gateT + (size_t)e * BTOK;
    __shared__ unsigned hist[256];
    __shared__ int pre[256];
    __shared__ unsigned sh_prefix;
    __shared__ int sh_rem;
    __shared__ unsigned cnt_s;
    if (t == 0) { sh_prefix = 0; sh_rem = KCAP; cnt_s = 0; }
    __syncthreads();
    for (int pass = 0; pass < 4; pass++) {
        int shift = 24 - pass * 8;
        hist[t] = 0;
        __syncthreads();
        unsigned pfx = sh_prefix;
        for (int i = t; i < BTOK; i += 256) {
            unsigned key = __float_as_uint(g[i]);
            if (pass == 0 || (key >> (shift + 8)) == pfx)
                atomicAdd(&hist[(key >> shift) & 255u], 1u);
        }
        __syncthreads();
        if (t == 0) {
            int rem = sh_rem, cum = 0, d = 0;
            for (int dd = 255; dd >= 0; dd--) {
                cum += (int)hist[dd];
                if (cum >= rem) { d = dd; break; }
            }
            sh_rem = rem - (cum - (int)hist[d]);
            sh_prefix = (pfx << 8) | (unsigned)d;
        }
        __syncthreads();
    }
    unsigned cutoff = sh_prefix;
    int base = t * 32;
    int ngt_t = 0, tie_t = 0;
    for (int j = 0; j < 32; j++) {
        unsigned key = __float_as_uint(g[base + j]);
        ngt_t += (key > cutoff) ? 1 : 0;
        tie_t += (key == cutoff) ? 1 : 0;
    }
    hist[t] = (unsigned)ngt_t;
    pre[t] = tie_t;
    __syncthreads();
    for (int s = 128; s > 0; s >>= 1) {
        if (t < s) hist[t] += hist[t + s];
        __syncthreads();
    }
    int need = KCAP - (int)hist[0];           // ties to accept (lowest index first)
    for (int s = 1; s < 256; s <<= 1) {
        int v = (t >= s) ? pre[t - s] : 0;
        __syncthreads();
        pre[t] += v;
        __syncthreads();
    }
    int rank = pre[t] - tie_t;                // exclusive prefix of tie counts
    for (int j = 0; j < 32; j++) {
        int b = base + j;
        float gv = g[b];
        unsigned key = __float_as_uint(gv);
        bool sel = (key > cutoff);
        if (!sel && key == cutoff) { sel = (rank < need); rank++; }
        if (sel) {
            unsigned pos = atomicAdd(&cnt_s, 1u);
            idx_list[(size_t)e * KCAP + pos] = b;
            wt_list[(size_t)e * KCAP + pos] = gv;
            inv[(size_t)e * BTOK + b] = (int)pos;
        }
    }
}

// ============ 128x256 GEMMs, 8 waves (64x64/wave), BK=32, ring-2 dbuf ============
// Ring-2: ~49 KB LDS, vmcnt(0) drain per K-step. Race audit: stage at kt writes slot
// (kt+1)&1, disjoint from read slot kt&1; that slot's readers finished at kt-1 behind
// its barrier; vmcnt(0)+barrier at end of kt publishes the stage before its reads.
// Swizzle (rule #21, both-sides, verified r4/r5): global chunk ((lane&3)^((lane>>3)&3))<<4,
// ds_read chunk (kg^((fr>>1)&3))<<4. Grid 1D, e = bid&7 (expert-per-XCD).
// NEW r14: LDS-staged vectorized epilogue — after the K-loop the staging pool is dead;
// stage the 128x256 bf16 output as two 128x128 half-tiles (EPAD=136: rows 272B, 16B
// aligned; hi-lanes 16 banks apart = free 2-way) aliased over the pool (dynamic smem),
// then b128 readback + global_store_dwordx4 (was: 64 scalar 2B stores/thread, ~25%
// write amplification: WRITE_SIZE 160 MB vs 128 MB payload).

#define ASLOT 4096   // ushorts per A slot (128 rows x 32)
#define BSLOT 8192   // ushorts per B slot (256 rows x 32)
#define POOLB 49152  // staging pool bytes (2*ASLOT + 2*BSLOT ushorts)
#define EPAD 136

// gemm1: h[e][m][n] = relu(xb[toks[e][m]] @ w1t[e][n] + b1[e][n])
__global__ __launch_bounds__(512, 4) void gemm1_kernel(
    const unsigned short* __restrict__ xb, const unsigned short* __restrict__ w1t,
    const float* __restrict__ b1, const int* __restrict__ idx_list,
    unsigned short* __restrict__ h) {
    extern __shared__ char pool[];
    unsigned short* As = (unsigned short*)pool;
    unsigned short* Bs = (unsigned short*)(pool + 2 * ASLOT * 2);
    int* toks = (int*)(pool + POOLB);
    int bid = blockIdx.x;
    int e = bid & 7, idx = bid >> 3;          // 256 blocks per expert
    int m0 = (idx & 15) * 128, n0 = (idx >> 4) * 256;
    w1t      += (size_t)e * DDIM * HDIM;
    b1       += (size_t)e * HDIM;
    idx_list += (size_t)e * KCAP;
    h        += (size_t)e * KCAP * HDIM;
    int t = threadIdx.x;
    if (t < 128) toks[t] = idx_list[m0 + t];
    __syncthreads();
    int w = t >> 6, lane = t & 63, l4 = lane >> 2;
    unsigned swz = (unsigned)(((lane & 3) ^ ((lane >> 3) & 3)) << 4);
    const char* pa  = (const char*)(xb + (size_t)toks[w * 16 + l4] * DDIM) + swz;
    const char* pb0 = (const char*)(w1t + (size_t)(n0 + w * 16 + l4) * DDIM) + swz;
    const char* pb1 = (const char*)(w1t + (size_t)(n0 + 128 + w * 16 + l4) * DDIM) + swz;
    unsigned short* da  = As + (w * 16) * 32;          // wave-uniform dests
    unsigned short* db0 = Bs + (w * 16) * 32;
    unsigned short* db1 = Bs + (128 + w * 16) * 32;
#define ST1(slot, koff) do {                                         \
    gl_lds16(pa  + (koff), da  + (slot) * ASLOT);                    \
    gl_lds16(pb0 + (koff), db0 + (slot) * BSLOT);                    \
    gl_lds16(pb1 + (koff), db1 + (slot) * BSLOT); } while (0)
    int wm = w >> 2, wn = w & 3;
    int fr = lane & 15, kg = lane >> 4;
    unsigned koffr = (unsigned)((kg ^ ((fr >> 1) & 3)) << 4);
    const int NT = DDIM / 32;   // 32
    f32x4 acc[4][4] = {};
    ST1(0, 0);
    asm volatile("s_waitcnt vmcnt(0)" ::: "memory");
    __builtin_amdgcn_s_barrier();
    for (int kt = 0; kt < NT; kt++) {
        if (kt + 1 < NT) ST1((kt + 1) & 1, (size_t)(kt + 1) * 64);
        const char* ab = (const char*)As + (kt & 1) * (ASLOT * 2);
        const char* bb = (const char*)Bs + (kt & 1) * (BSLOT * 2);
        bf16x8 af[4], bf[4];
#pragma unroll
        for (int mf = 0; mf < 4; mf++)
            af[mf] = *(const bf16x8*)(ab + (wm * 64 + mf * 16 + fr) * 64 + koffr);
#pragma unroll
        for (int nf = 0; nf < 4; nf++)
            bf[nf] = *(const bf16x8*)(bb + (wn * 64 + nf * 16 + fr) * 64 + koffr);
        __builtin_amdgcn_s_setprio(1);
#pragma unroll
        for (int mf = 0; mf < 4; mf++)
#pragma unroll
            for (int nf = 0; nf < 4; nf++)
                acc[mf][nf] = __builtin_amdgcn_mfma_f32_16x16x32_bf16(
                    af[mf], bf[nf], acc[mf][nf], 0, 0, 0);
        __builtin_amdgcn_s_setprio(0);
        if (kt + 1 < NT) {
            asm volatile("s_waitcnt vmcnt(0)" ::: "memory");
            __builtin_amdgcn_s_barrier();
        }
    }
#undef ST1
    // ---- LDS-staged vectorized epilogue ----
    int hi = lane >> 4;
    float biasv[4];
#pragma unroll
    for (int nf = 0; nf < 4; nf++) biasv[nf] = b1[n0 + wn * 64 + nf * 16 + fr];
    unsigned short (*tile)[EPAD] = (unsigned short (*)[EPAD])pool;
#pragma unroll
    for (int p = 0; p < 2; p++) {
        __syncthreads();                       // pool free (K-loop / prev readback done)
        if ((wn >> 1) == p) {
            int lc = (wn & 1) * 64;
#pragma unroll
            for (int mf = 0; mf < 4; mf++)
#pragma unroll
                for (int nf = 0; nf < 4; nf++)
#pragma unroll
                    for (int r = 0; r < 4; r++)
                        tile[wm * 64 + mf * 16 + hi * 4 + r][lc + nf * 16 + fr] =
                            f2bf(fmaxf(acc[mf][nf][r] + biasv[nf], 0.f));
        }
        __syncthreads();
#pragma unroll
        for (int ps = 0; ps < 4; ps++) {
            int row = ps * 32 + (t >> 4);
            int c16 = t & 15;
            *(int4*)(h + (size_t)(m0 + row) * HDIM + n0 + p * 128 + c16 * 8) =
                *(const int4*)&tile[row][c16 * 8];
        }
    }
}

// gemm2y: yb[e][m][n] = bf16( wt[e][m] * (h[e][m] @ w2t[e][n] + b2[e][n]) )
__global__ __launch_bounds__(512, 4) void gemm2y_kernel(
    const unsigned short* __restrict__ h, const unsigned short* __restrict__ w2t,
    const float* __restrict__ b2, const float* __restrict__ wt_list,
    unsigned short* __restrict__ yb) {
    extern __shared__ char pool[];
    unsigned short* As = (unsigned short*)pool;
    unsigned short* Bs = (unsigned short*)(pool + 2 * ASLOT * 2);
    float* wts = (float*)(pool + POOLB);
    int bid = blockIdx.x;
    int e = bid & 7, idx = bid >> 3;          // 64 blocks per expert
    int m0 = (idx & 15) * 128, n0 = (idx >> 4) * 256;
    h       += (size_t)e * KCAP * HDIM;
    w2t     += (size_t)e * DDIM * HDIM;
    b2      += (size_t)e * DDIM;
    wt_list += (size_t)e * KCAP;
    yb      += (size_t)e * KCAP * DDIM;
    int t = threadIdx.x;
    if (t < 128) wts[t] = wt_list[m0 + t];
    __syncthreads();
    int w = t >> 6, lane = t & 63, l4 = lane >> 2;
    unsigned swz = (unsigned)(((lane & 3) ^ ((lane >> 3) & 3)) << 4);
    const char* pa  = (const char*)(h + (size_t)(m0 + w * 16 + l4) * HDIM) + swz;
    const char* pb0 = (const char*)(w2t + (size_t)(n0 + w * 16 + l4) * HDIM) + swz;
    const char* pb1 = (const char*)(w2t + (size_t)(n0 + 128 + w * 16 + l4) * HDIM) + swz;
    unsigned short* da  = As + (w * 16) * 32;
    unsigned short* db0 = Bs + (w * 16) * 32;
    unsigned short* db1 = Bs + (128 + w * 16) * 32;
#define ST2(slot, koff) do {                                         \
    gl_lds16(pa  + (koff), da  + (slot) * ASLOT);                    \
    gl_lds16(pb0 + (koff), db0 + (slot) * BSLOT);                    \
    gl_lds16(pb1 + (koff), db1 + (slot) * BSLOT); } while (0)
    int wm = w >> 2, wn = w & 3;
    int fr = lane & 15, kg = lane >> 4;
    unsigned koffr = (unsigned)((kg ^ ((fr >> 1) & 3)) << 4);
    const int NT = HDIM / 32;                 // 128
    f32x4 acc[4][4] = {};
    ST2(0, 0);
    asm volatile("s_waitcnt vmcnt(0)" ::: "memory");
    __builtin_amdgcn_s_barrier();
    for (int kt = 0; kt < NT; kt++) {
        if (kt + 1 < NT) ST2((kt + 1) & 1, (size_t)(kt + 1) * 64);
        const char* ab = (const char*)As + (kt & 1) * (ASLOT * 2);
        const char* bb = (const char*)Bs + (kt & 1) * (BSLOT * 2);
        bf16x8 af[4], bf[4];
#pragma unroll
        for (int mf = 0; mf < 4; mf++)
            af[mf] = *(const bf16x8*)(ab + (wm * 64 + mf * 16 + fr) * 64 + koffr);
#pragma unroll
        for (int nf = 0; nf < 4; nf++)
            bf[nf] = *(const bf16x8*)(bb + (wn * 64 + nf * 16 + fr) * 64 + koffr);
        __builtin_amdgcn_s_setprio(1);
#pragma unroll
        for (int mf = 0; mf < 4; mf++)
#pragma unroll
            for (int nf = 0; nf < 4; nf++)
                acc[mf][nf] = __builtin_amdgcn_mfma_f32_16x16x32_bf16(
                    af[mf], bf[nf], acc[mf][nf], 0, 0, 0);
        __builtin_amdgcn_s_setprio(0);
        if (kt + 1 < NT) {
            asm volatile("s_waitcnt vmcnt(0)" ::: "memory");
            __builtin_amdgcn_s_barrier();
        }
    }
#undef ST2
    // ---- LDS-staged vectorized epilogue ----
    int hi = lane >> 4;
    float biasv[4];
#pragma unroll
    for (int nf = 0; nf < 4; nf++) biasv[nf] = b2[n0 + wn * 64 + nf * 16 + fr];
    unsigned short (*tile)[EPAD] = (unsigned short (*)[EPAD])pool;
#pragma unroll
    for (int p = 0; p < 2; p++) {
        __syncthreads();
        if ((wn >> 1) == p) {
            int lc = (wn & 1) * 64;
#pragma unroll
            for (int mf = 0; mf < 4; mf++)
#pragma unroll
                for (int nf = 0; nf < 4; nf++)
#pragma unroll
                    for (int r = 0; r < 4; r++) {
                        int lrow = wm * 64 + mf * 16 + hi * 4 + r;
                        tile[lrow][lc + nf * 16 + fr] =
                            f2bf(wts[lrow] * (acc[mf][nf][r] + biasv[nf]));
                    }
        }
        __syncthreads();
#pragma unroll
        for (int ps = 0; ps < 4; ps++) {
            int row = ps * 32 + (t >> 4);
            int c16 = t & 15;
            *(int4*)(yb + (size_t)(m0 + row) * DDIM + n0 + p * 128 + c16 * 8) =
                *(const int4*)&tile[row][c16 * 8];
        }
    }
}

// ---------------- combine: out[b] = sum_e bf2f(yb[e][inv[e][b]]) ----------------
__global__ __launch_bounds__(256) void combine_kernel(
    const unsigned short* __restrict__ yb, const int* __restrict__ inv,
    float* __restrict__ out) {
    int b = blockIdx.x, t = threadIdx.x;
    float4 acc = {0.f, 0.f, 0.f, 0.f};
#pragma unroll
    for (int e = 0; e < NEXP; e++) {
        int s = inv[(size_t)e * BTOK + b];
        if (s >= 0) {
            short4 v = *(const short4*)(yb + ((size_t)e * KCAP + s) * DDIM + t * 4);
            acc.x += bf2f((unsigned short)v.x);
            acc.y += bf2f((unsigned short)v.y);
            acc.z += bf2f((unsigned short)v.z);
            acc.w += bf2f((unsigned short)v.w);
        }
    }
    *(float4*)(out + (size_t)b * DDIM + t * 4) = acc;
}

extern "C" void kernel_launch(void* const* d_in, const int* in_sizes, int n_in,
                              void* d_out, int out_size, void* d_ws, size_t ws_size,
                              hipStream_t stream) {
    const float* x  = (const float*)d_in[0];
    const float* Wr = (const float*)d_in[1];
    const float* br = (const float*)d_in[2];
    const float* W1 = (const float*)d_in[3];
    const float* b1 = (const float*)d_in[4];
    const float* W2 = (const float*)d_in[5];
    const float* b2 = (const float*)d_in[6];
    float* out = (float*)d_out;

    char* ws = (char*)d_ws;
    float*    gateT    = (float*)ws;                       // 256 KB
    int*      idx_list = (int*)(ws + 327680);              // 64 KB
    float*    wt_list  = (float*)(ws + 393216);            // 64 KB
    int*      inv      = (int*)(ws + 458752);              // 256 KB
    unsigned short* xbuf = (unsigned short*)(ws + 1 * MB);    // 16 MB
    unsigned short* w1t  = (unsigned short*)(ws + 17 * MB);   // 64 MB
    unsigned short* w2t  = (unsigned short*)(ws + 81 * MB);   // 64 MB
    unsigned short* hbuf = (unsigned short*)(ws + 145 * MB);  // 128 MB
    unsigned short* yb   = (unsigned short*)(ws + 273 * MB);  // 32 MB (bf16)
    const size_t NEED = 305 * MB;
    if (ws_size < NEED) return;

    // prep: 2048 router blocks (+inv init) || 16384 transpose blocks, one dispatch
    prep_kernel<<<dim3(BTOK / 4 + 16384), 256, 0, stream>>>(
        x, Wr, br, W1, W2, gateT, xbuf, w1t, w2t, inv);
    route_kernel<<<dim3(NEXP), 256, 0, stream>>>(gateT, idx_list, wt_list, inv);

    // 1D grids, expert = bid&7 (expert-per-XCD swizzle); dyn smem = pool + toks/wts
    gemm1_kernel<<<dim3((KCAP / 128) * (HDIM / 256) * NEXP), 512, POOLB + 512, stream>>>(
        xbuf, w1t, b1, idx_list, hbuf);
    gemm2y_kernel<<<dim3((KCAP / 128) * (DDIM / 256) * NEXP), 512, POOLB + 512, stream>>>(
        hbuf, w2t, b2, wt_list, yb);
    combine_kernel<<<dim3(BTOK), 256, 0, stream>>>(yb, inv, out);
}

// Round 15
// 511.535 us; speedup vs baseline: 1.0173x; 1.0173x over previous
//
#include <hip/hip_runtime.h>
#include <hip/hip_bf16.h>

#define BTOK 8192
#define DDIM 1024
#define NEXP 8
#define KCAP 2048
#define HDIM 4096
#define MB ((size_t)1048576)

typedef __attribute__((ext_vector_type(4))) float f32x4;
typedef __attribute__((ext_vector_type(8))) short bf16x8;

__device__ __forceinline__ unsigned short f2bf(float f) {
    union { float f; unsigned u; } v; v.f = f;
    unsigned r = v.u + 0x7fffu + ((v.u >> 16) & 1u);   // RNE
    return (unsigned short)(r >> 16);
}
__device__ __forceinline__ float bf2f(unsigned short u) {
    union { unsigned u; float f; } v; v.u = ((unsigned)u) << 16;
    return v.f;
}

typedef __attribute__((address_space(3))) unsigned int lds_u32;
typedef __attribute__((address_space(1))) const unsigned int glb_u32;
__device__ __forceinline__ void gl_lds16(const void* g, void* l) {
    __builtin_amdgcn_global_load_lds((glb_u32*)g, (lds_u32*)l, 16, 0, 0);
}

// ======== prep: router (blocks 0..2047, + inv=-1 init) and W-transpose (blocks 2048+) ========
__global__ __launch_bounds__(256) void prep_kernel(
    const float* __restrict__ x, const float* __restrict__ Wr,
    const float* __restrict__ br, const float* __restrict__ W1,
    const float* __restrict__ W2, float* __restrict__ gateT,
    unsigned short* __restrict__ xb, unsigned short* __restrict__ w1t,
    unsigned short* __restrict__ w2t, int* __restrict__ inv) {
    __shared__ char smem[NEXP * DDIM * 4];     // router: wr_s 32KB; tcvt: tile 9KB
    int bid = blockIdx.x;
    int t = threadIdx.x;
    if (bid < BTOK / 4) {
        // ---- router role: gateT[e][b] = softmax(x@Wr + br); x->bf16; inv init ----
        float (*wr_s)[DDIM] = (float (*)[DDIM])smem;
        for (int i = t; i < NEXP * DDIM; i += 256) {
            int e = i >> 10, d = i & 1023;
            wr_s[e][d] = Wr[d * NEXP + e];
        }
        if (t < 32) inv[(size_t)(t >> 2) * BTOK + bid * 4 + (t & 3)] = -1;  // all 8 e x 4 b
        __syncthreads();
        int wid = t >> 6, lane = t & 63;
        int b = bid * 4 + wid;
        const float4* xr = (const float4*)(x + (size_t)b * DDIM);
        float4 xv[4];
#pragma unroll
        for (int j = 0; j < 4; j++) xv[j] = xr[j * 64 + lane];
#pragma unroll
        for (int j = 0; j < 4; j++) {
            short4 s;
            s.x = (short)f2bf(xv[j].x); s.y = (short)f2bf(xv[j].y);
            s.z = (short)f2bf(xv[j].z); s.w = (short)f2bf(xv[j].w);
            *(short4*)(xb + (size_t)b * DDIM + (j * 64 + lane) * 4) = s;
        }
        double acc[NEXP];
#pragma unroll
        for (int e = 0; e < NEXP; e++) {
            double a = 0.0;
#pragma unroll
            for (int j = 0; j < 4; j++) {
                float4 wv = ((const float4*)&wr_s[e][0])[j * 64 + lane];
                a += (double)xv[j].x * wv.x + (double)xv[j].y * wv.y
                   + (double)xv[j].z * wv.z + (double)xv[j].w * wv.w;
            }
#pragma unroll
            for (int s = 1; s < 64; s <<= 1) a += __shfl_xor(a, s, 64);
            acc[e] = a + (double)br[e];
        }
        if (lane == 0) {
            double mx = acc[0];
#pragma unroll
            for (int e = 1; e < NEXP; e++) mx = fmax(mx, acc[e]);
            double p[NEXP]; double ssum = 0.0;
#pragma unroll
            for (int e = 0; e < NEXP; e++) { p[e] = exp(acc[e] - mx); ssum += p[e]; }
            double is = 1.0 / ssum;
#pragma unroll
            for (int e = 0; e < NEXP; e++) gateT[e * BTOK + b] = (float)(p[e] * is);
        }
    } else {
        // ---- tcvt role: W1 (z<8) / W2 (z>=8), [R][C] f32 -> [C][R] bf16 ----
        int z16 = bid - BTOK / 4;          // 0..16383
        int z = z16 >> 10, bx = z16 & 1023;
        const float* src; unsigned short* dst; int R, C;
        if (z < 8) { src = W1 + (size_t)z * DDIM * HDIM; dst = w1t + (size_t)z * DDIM * HDIM; R = DDIM; C = HDIM; }
        else       { src = W2 + (size_t)(z - 8) * DDIM * HDIM; dst = w2t + (size_t)(z - 8) * DDIM * HDIM; R = HDIM; C = DDIM; }
        int ntx = C >> 6;
        int c0 = (bx % ntx) * 64, r0 = (bx / ntx) * 64;
        unsigned short (*tile)[72] = (unsigned short (*)[72])smem;
        int cq = t & 15, rr = t >> 4;
#pragma unroll
        for (int ri = 0; ri < 4; ri++) {
            int r = ri * 16 + rr;
            float4 v = *(const float4*)(src + (size_t)(r0 + r) * C + c0 + cq * 4);
            tile[cq * 4 + 0][r] = f2bf(v.x);
            tile[cq * 4 + 1][r] = f2bf(v.y);
            tile[cq * 4 + 2][r] = f2bf(v.z);
            tile[cq * 4 + 3][r] = f2bf(v.w);
        }
        __syncthreads();
        int rq = t & 15, cc = t >> 4;
#pragma unroll
        for (int ci = 0; ci < 4; ci++) {
            int c = ci * 16 + cc;
            *(short4*)(dst + (size_t)(c0 + c) * R + r0 + rq * 4) = *(const short4*)&tile[c][rq * 4];
        }
    }
}

// ---- fused route: radix select + compaction + ties + inverse map, one block/expert ----
__global__ __launch_bounds__(256) void route_kernel(
    const float* __restrict__ gateT, int* __restrict__ idx_list,
    float* __restrict__ wt_list, int* __restrict__ inv) {
    int e = blockIdx.x, t = threadIdx.x;
    const float* g = gateT + (size_t)e * BTOK;
    __shared__ unsigned hist[256];
    __shared__ int pre[256];
    __shared__ unsigned sh_prefix;
    __shared__ int sh_rem;
    __shared__ unsigned cnt_s;
    if (t == 0) { sh_prefix = 0; sh_rem = KCAP; cnt_s = 0; }
    __syncthreads();
    for (int pass = 0; pass < 4; pass++) {
        int shift = 24 - pass * 8;
        hist[t] = 0;
        __syncthreads();
        unsigned pfx = sh_prefix;
        for (int i = t; i < BTOK; i += 256) {
            unsigned key = __float_as_uint(g[i]);
            if (pass == 0 || (key >> (shift + 8)) == pfx)
                atomicAdd(&hist[(key >> shift) & 255u], 1u);
        }
        __syncthreads();
        if (t == 0) {
            int rem = sh_rem, cum = 0, d = 0;
            for (int dd = 255; dd >= 0; dd--) {
                cum += (int)hist[dd];
                if (cum >= rem) { d = dd; break; }
            }
            sh_rem = rem - (cum - (int)hist[d]);
            sh_prefix = (pfx << 8) | (unsigned)d;
        }
        __syncthreads();
    }
    unsigned cutoff = sh_prefix;
    int base = t * 32;
    int ngt_t = 0, tie_t = 0;
    for (int j = 0; j < 32; j++) {
        unsigned key = __float_as_uint(g[base + j]);
        ngt_t += (key > cutoff) ? 1 : 0;
        tie_t += (key == cutoff) ? 1 : 0;
    }
    hist[t] = (unsigned)ngt_t;
    pre[t] = tie_t;
    __syncthreads();
    for (int s = 128; s > 0; s >>= 1) {
        if (t < s) hist[t] += hist[t + s];
        __syncthreads();
    }
    int need = KCAP - (int)hist[0];           // ties to accept (lowest index first)
    for (int s = 1; s < 256; s <<= 1) {
        int v = (t >= s) ? pre[t - s] : 0;
        __syncthreads();
        pre[t] += v;
        __syncthreads();
    }
    int rank = pre[t] - tie_t;                // exclusive prefix of tie counts
    for (int j = 0; j < 32; j++) {
        int b = base + j;
        float gv = g[b];
        unsigned key = __float_as_uint(gv);
        bool sel = (key > cutoff);
        if (!sel && key == cutoff) { sel = (rank < need); rank++; }
        if (sel) {
            unsigned pos = atomicAdd(&cnt_s, 1u);
            idx_list[(size_t)e * KCAP + pos] = b;
            wt_list[(size_t)e * KCAP + pos] = gv;
            inv[(size_t)e * BTOK + b] = (int)pos;
        }
    }
}

// ============ 128x256 GEMMs, 8 waves (64x64/wave), BK=32, ring-2 dbuf ============
// Ring-2: ~49 KB LDS, vmcnt(0) drain per K-step. Race audit: stage at kt writes slot
// (kt+1)&1, disjoint from read slot kt&1; that slot's readers finished at kt-1 behind
// its barrier; vmcnt(0)+barrier at end of kt publishes the stage before its reads.
// Swizzle (rule #21, both-sides, verified r4/r5): global chunk ((lane&3)^((lane>>3)&3))<<4,
// ds_read chunk (kg^((fr>>1)&3))<<4. Grid 1D, e = bid&7 (expert-per-XCD).
// gemm1 (2048 blocks, 3/CU resident): LDS-staged vectorized epilogue — r14-verified
// WRITE_SIZE 160->128 MB exact, -6 us. gemm2y (512 blocks, only 2/CU resident): staged
// epilogue NOT amortized (r14 A/B regressed) -> scalar epilogue (r13 form).

#define ASLOT 4096   // ushorts per A slot (128 rows x 32)
#define BSLOT 8192   // ushorts per B slot (256 rows x 32)
#define POOLB 49152  // staging pool bytes
#define EPAD 136

// gemm1: h[e][m][n] = relu(xb[toks[e][m]] @ w1t[e][n] + b1[e][n]); staged epilogue
__global__ __launch_bounds__(512, 4) void gemm1_kernel(
    const unsigned short* __restrict__ xb, const unsigned short* __restrict__ w1t,
    const float* __restrict__ b1, const int* __restrict__ idx_list,
    unsigned short* __restrict__ h) {
    extern __shared__ char pool[];
    unsigned short* As = (unsigned short*)pool;
    unsigned short* Bs = (unsigned short*)(pool + 2 * ASLOT * 2);
    int* toks = (int*)(pool + POOLB);
    int bid = blockIdx.x;
    int e = bid & 7, idx = bid >> 3;          // 256 blocks per expert
    int m0 = (idx & 15) * 128, n0 = (idx >> 4) * 256;
    w1t      += (size_t)e * DDIM * HDIM;
    b1       += (size_t)e * HDIM;
    idx_list += (size_t)e * KCAP;
    h        += (size_t)e * KCAP * HDIM;
    int t = threadIdx.x;
    if (t < 128) toks[t] = idx_list[m0 + t];
    __syncthreads();
    int w = t >> 6, lane = t & 63, l4 = lane >> 2;
    unsigned swz = (unsigned)(((lane & 3) ^ ((lane >> 3) & 3)) << 4);
    const char* pa  = (const char*)(xb + (size_t)toks[w * 16 + l4] * DDIM) + swz;
    const char* pb0 = (const char*)(w1t + (size_t)(n0 + w * 16 + l4) * DDIM) + swz;
    const char* pb1 = (const char*)(w1t + (size_t)(n0 + 128 + w * 16 + l4) * DDIM) + swz;
    unsigned short* da  = As + (w * 16) * 32;          // wave-uniform dests
    unsigned short* db0 = Bs + (w * 16) * 32;
    unsigned short* db1 = Bs + (128 + w * 16) * 32;
#define ST1(slot, koff) do {                                         \
    gl_lds16(pa  + (koff), da  + (slot) * ASLOT);                    \
    gl_lds16(pb0 + (koff), db0 + (slot) * BSLOT);                    \
    gl_lds16(pb1 + (koff), db1 + (slot) * BSLOT); } while (0)
    int wm = w >> 2, wn = w & 3;
    int fr = lane & 15, kg = lane >> 4;
    unsigned koffr = (unsigned)((kg ^ ((fr >> 1) & 3)) << 4);
    const int NT = DDIM / 32;   // 32
    f32x4 acc[4][4] = {};
    ST1(0, 0);
    asm volatile("s_waitcnt vmcnt(0)" ::: "memory");
    __builtin_amdgcn_s_barrier();
    for (int kt = 0; kt < NT; kt++) {
        if (kt + 1 < NT) ST1((kt + 1) & 1, (size_t)(kt + 1) * 64);
        const char* ab = (const char*)As + (kt & 1) * (ASLOT * 2);
        const char* bb = (const char*)Bs + (kt & 1) * (BSLOT * 2);
        bf16x8 af[4], bf[4];
#pragma unroll
        for (int mf = 0; mf < 4; mf++)
            af[mf] = *(const bf16x8*)(ab + (wm * 64 + mf * 16 + fr) * 64 + koffr);
#pragma unroll
        for (int nf = 0; nf < 4; nf++)
            bf[nf] = *(const bf16x8*)(bb + (wn * 64 + nf * 16 + fr) * 64 + koffr);
        __builtin_amdgcn_s_setprio(1);
#pragma unroll
        for (int mf = 0; mf < 4; mf++)
#pragma unroll
            for (int nf = 0; nf < 4; nf++)
                acc[mf][nf] = __builtin_amdgcn_mfma_f32_16x16x32_bf16(
                    af[mf], bf[nf], acc[mf][nf], 0, 0, 0);
        __builtin_amdgcn_s_setprio(0);
        if (kt + 1 < NT) {
            asm volatile("s_waitcnt vmcnt(0)" ::: "memory");
            __builtin_amdgcn_s_barrier();
        }
    }
#undef ST1
    // ---- LDS-staged vectorized epilogue (r14-verified on gemm1) ----
    int hi = lane >> 4;
    float biasv[4];
#pragma unroll
    for (int nf = 0; nf < 4; nf++) biasv[nf] = b1[n0 + wn * 64 + nf * 16 + fr];
    unsigned short (*tile)[EPAD] = (unsigned short (*)[EPAD])pool;
#pragma unroll
    for (int p = 0; p < 2; p++) {
        __syncthreads();                       // pool free (K-loop / prev readback done)
        if ((wn >> 1) == p) {
            int lc = (wn & 1) * 64;
#pragma unroll
            for (int mf = 0; mf < 4; mf++)
#pragma unroll
                for (int nf = 0; nf < 4; nf++)
#pragma unroll
                    for (int r = 0; r < 4; r++)
                        tile[wm * 64 + mf * 16 + hi * 4 + r][lc + nf * 16 + fr] =
                            f2bf(fmaxf(acc[mf][nf][r] + biasv[nf], 0.f));
        }
        __syncthreads();
#pragma unroll
        for (int ps = 0; ps < 4; ps++) {
            int row = ps * 32 + (t >> 4);
            int c16 = t & 15;
            *(int4*)(h + (size_t)(m0 + row) * HDIM + n0 + p * 128 + c16 * 8) =
                *(const int4*)&tile[row][c16 * 8];
        }
    }
}

// gemm2y: yb[e][m][n] = bf16( wt[e][m] * (h[e][m] @ w2t[e][n] + b2[e][n]) ); scalar epilogue
__global__ __launch_bounds__(512, 4) void gemm2y_kernel(
    const unsigned short* __restrict__ h, const unsigned short* __restrict__ w2t,
    const float* __restrict__ b2, const float* __restrict__ wt_list,
    unsigned short* __restrict__ yb) {
    __shared__ unsigned short As[2 * ASLOT];
    __shared__ unsigned short Bs[2 * BSLOT];
    __shared__ float wts[128];
    int bid = blockIdx.x;
    int e = bid & 7, idx = bid >> 3;          // 64 blocks per expert
    int m0 = (idx & 15) * 128, n0 = (idx >> 4) * 256;
    h       += (size_t)e * KCAP * HDIM;
    w2t     += (size_t)e * DDIM * HDIM;
    b2      += (size_t)e * DDIM;
    wt_list += (size_t)e * KCAP;
    yb      += (size_t)e * KCAP * DDIM;
    int t = threadIdx.x;
    if (t < 128) wts[t] = wt_list[m0 + t];
    __syncthreads();
    int w = t >> 6, lane = t & 63, l4 = lane >> 2;
    unsigned swz = (unsigned)(((lane & 3) ^ ((lane >> 3) & 3)) << 4);
    const char* pa  = (const char*)(h + (size_t)(m0 + w * 16 + l4) * HDIM) + swz;
    const char* pb0 = (const char*)(w2t + (size_t)(n0 + w * 16 + l4) * HDIM) + swz;
    const char* pb1 = (const char*)(w2t + (size_t)(n0 + 128 + w * 16 + l4) * HDIM) + swz;
    unsigned short* da  = As + (w * 16) * 32;
    unsigned short* db0 = Bs + (w * 16) * 32;
    unsigned short* db1 = Bs + (128 + w * 16) * 32;
#define ST2(slot, koff) do {                                         \
    gl_lds16(pa  + (koff), da  + (slot) * ASLOT);                    \
    gl_lds16(pb0 + (koff), db0 + (slot) * BSLOT);                    \
    gl_lds16(pb1 + (koff), db1 + (slot) * BSLOT); } while (0)
    int wm = w >> 2, wn = w & 3;
    int fr = lane & 15, kg = lane >> 4;
    unsigned koffr = (unsigned)((kg ^ ((fr >> 1) & 3)) << 4);
    const int NT = HDIM / 32;                 // 128
    f32x4 acc[4][4] = {};
    ST2(0, 0);
    asm volatile("s_waitcnt vmcnt(0)" ::: "memory");
    __builtin_amdgcn_s_barrier();
    for (int kt = 0; kt < NT; kt++) {
        if (kt + 1 < NT) ST2((kt + 1) & 1, (size_t)(kt + 1) * 64);
        const char* ab = (const char*)As + (kt & 1) * (ASLOT * 2);
        const char* bb = (const char*)Bs + (kt & 1) * (BSLOT * 2);
        bf16x8 af[4], bf[4];
#pragma unroll
        for (int mf = 0; mf < 4; mf++)
            af[mf] = *(const bf16x8*)(ab + (wm * 64 + mf * 16 + fr) * 64 + koffr);
#pragma unroll
        for (int nf = 0; nf < 4; nf++)
            bf[nf] = *(const bf16x8*)(bb + (wn * 64 + nf * 16 + fr) * 64 + koffr);
        __builtin_amdgcn_s_setprio(1);
#pragma unroll
        for (int mf = 0; mf < 4; mf++)
#pragma unroll
            for (int nf = 0; nf < 4; nf++)
                acc[mf][nf] = __builtin_amdgcn_mfma_f32_16x16x32_bf16(
                    af[mf], bf[nf], acc[mf][nf], 0, 0, 0);
        __builtin_amdgcn_s_setprio(0);
        if (kt + 1 < NT) {
            asm volatile("s_waitcnt vmcnt(0)" ::: "memory");
            __builtin_amdgcn_s_barrier();
        }
    }
#undef ST2
    int hi = lane >> 4;
#pragma unroll
    for (int nf = 0; nf < 4; nf++) {
        int col = n0 + wn * 64 + nf * 16 + fr;
        float bias = b2[col];
#pragma unroll
        for (int mf = 0; mf < 4; mf++) {
            int r0 = wm * 64 + mf * 16 + hi * 4;
#pragma unroll
            for (int r = 0; r < 4; r++) {
                int lrow = r0 + r;
                yb[(size_t)(m0 + lrow) * DDIM + col] = f2bf(wts[lrow] * (acc[mf][nf][r] + bias));
            }
        }
    }
}

// ---------------- combine: out[b] = sum_e bf2f(yb[e][inv[e][b]]) ----------------
__global__ __launch_bounds__(256) void combine_kernel(
    const unsigned short* __restrict__ yb, const int* __restrict__ inv,
    float* __restrict__ out) {
    int b = blockIdx.x, t = threadIdx.x;
    float4 acc = {0.f, 0.f, 0.f, 0.f};
#pragma unroll
    for (int e = 0; e < NEXP; e++) {
        int s = inv[(size_t)e * BTOK + b];
        if (s >= 0) {
            short4 v = *(const short4*)(yb + ((size_t)e * KCAP + s) * DDIM + t * 4);
            acc.x += bf2f((unsigned short)v.x);
            acc.y += bf2f((unsigned short)v.y);
            acc.z += bf2f((unsigned short)v.z);
            acc.w += bf2f((unsigned short)v.w);
        }
    }
    *(float4*)(out + (size_t)b * DDIM + t * 4) = acc;
}

extern "C" void kernel_launch(void* const* d_in, const int* in_sizes, int n_in,
                              void* d_out, int out_size, void* d_ws, size_t ws_size,
                              hipStream_t stream) {
    const float* x  = (const float*)d_in[0];
    const float* Wr = (const float*)d_in[1];
    const float* br = (const float*)d_in[2];
    const float* W1 = (const float*)d_in[3];
    const float* b1 = (const float*)d_in[4];
    const float* W2 = (const float*)d_in[5];
    const float* b2 = (const float*)d_in[6];
    float* out = (float*)d_out;

    char* ws = (char*)d_ws;
    float*    gateT    = (float*)ws;                       // 256 KB
    int*      idx_list = (int*)(ws + 327680);              // 64 KB
    float*    wt_list  = (float*)(ws + 393216);            // 64 KB
    int*      inv      = (int*)(ws + 458752);              // 256 KB
    unsigned short* xbuf = (unsigned short*)(ws + 1 * MB);    // 16 MB
    unsigned short* w1t  = (unsigned short*)(ws + 17 * MB);   // 64 MB
    unsigned short* w2t  = (unsigned short*)(ws + 81 * MB);   // 64 MB
    unsigned short* hbuf = (unsigned short*)(ws + 145 * MB);  // 128 MB
    unsigned short* yb   = (unsigned short*)(ws + 273 * MB);  // 32 MB (bf16)
    const size_t NEED = 305 * MB;
    if (ws_size < NEED) return;

    // prep: 2048 router blocks (+inv init) || 16384 transpose blocks, one dispatch
    prep_kernel<<<dim3(BTOK / 4 + 16384), 256, 0, stream>>>(
        x, Wr, br, W1, W2, gateT, xbuf, w1t, w2t, inv);
    route_kernel<<<dim3(NEXP), 256, 0, stream>>>(gateT, idx_list, wt_list, inv);

    // 1D grids, expert = bid&7 (expert-per-XCD swizzle); gemm1 dyn smem = pool + toks
    gemm1_kernel<<<dim3((KCAP / 128) * (HDIM / 256) * NEXP), 512, POOLB + 512, stream>>>(
        xbuf, w1t, b1, idx_list, hbuf);
    gemm2y_kernel<<<dim3((KCAP / 128) * (DDIM / 256) * NEXP), 512, 0, stream>>>(
        hbuf, w2t, b2, wt_list, yb);
    combine_kernel<<<dim3(BTOK), 256, 0, stream>>>(yb, inv, out);
}